// Round 1
// baseline (556.062 us; speedup 1.0000x reference)
//
#include <hip/hip_runtime.h>
#include <hip/hip_bf16.h>
#include <cstdint>

#define DEVI __device__ __forceinline__

using bf16x8 = __attribute__((ext_vector_type(8))) short;
using f32x4  = __attribute__((ext_vector_type(4))) float;

DEVI short f2b(float f) {
  __hip_bfloat16 h = __float2bfloat16(f);
  return *reinterpret_cast<short*>(&h);
}

DEVI f32x4 mfma16(bf16x8 a, bf16x8 b, f32x4 c) {
  return __builtin_amdgcn_mfma_f32_16x16x32_bf16(a, b, c, 0, 0, 0);
}

DEVI void gload_lds16(const void* g, void* l) {
  __builtin_amdgcn_global_load_lds(
      (const __attribute__((address_space(1))) void*)g,
      (__attribute__((address_space(3))) void*)l, 16, 0, 0);
}

DEVI float gelu_f(float x) {
  // tanh-approx gelu: 0.5x(1+tanh(0.79788456(x+0.044715x^3)))
  float u = 1.5957691216057308f * (x + 0.044715f * x * x * x); // 2z
  float e = __expf(u);
  float t = 1.f - 2.f / (e + 1.f); // tanh(z)
  return 0.5f * x * (1.f + t);
}

// ---------------- weight transpose + fp32->bf16 convert ----------------
// in: fp32 [R][Cc] row-major; out: bf16 [Cc][R]
__global__ void k_wt(const float* __restrict__ in, short* __restrict__ out,
                     int R, int Cc) {
  __shared__ float tile[32][33];
  int c0 = blockIdx.x * 32;
  int r0 = blockIdx.y * 32;
  int tx = threadIdx.x, ty = threadIdx.y;
  for (int i = ty; i < 32; i += 8) {
    int r = r0 + i, c = c0 + tx;
    tile[i][tx] = (r < R && c < Cc) ? in[(size_t)r * Cc + c] : 0.f;
  }
  __syncthreads();
  for (int i = ty; i < 32; i += 8) {
    int orow = c0 + i;   // out row = original col
    int ocol = r0 + tx;  // out col = original row
    if (orow < Cc && ocol < R) out[(size_t)orow * R + ocol] = f2b(tile[tx][i]);
  }
}

// ---------------- layernorm: fp32 in -> bf16 out (C=1024) ----------------
__global__ void k_layernorm(const float* __restrict__ x, const float* __restrict__ g,
                            const float* __restrict__ bta, short* __restrict__ out) {
  const int C = 1024;
  int row = blockIdx.x;
  const float* xr = x + (size_t)row * C;
  f32x4 v = *(const f32x4*)(xr + threadIdx.x * 4);
  float s = v[0] + v[1] + v[2] + v[3];
  float s2 = v[0]*v[0] + v[1]*v[1] + v[2]*v[2] + v[3]*v[3];
#pragma unroll
  for (int m = 1; m < 64; m <<= 1) { s += __shfl_xor(s, m); s2 += __shfl_xor(s2, m); }
  __shared__ float red[8];
  int w = threadIdx.x >> 6;
  if ((threadIdx.x & 63) == 0) { red[w] = s; red[4 + w] = s2; }
  __syncthreads();
  s = red[0] + red[1] + red[2] + red[3];
  s2 = red[4] + red[5] + red[6] + red[7];
  float mu = s * (1.f / 1024.f);
  float rstd = rsqrtf(s2 * (1.f / 1024.f) - mu * mu + 1e-5f);
#pragma unroll
  for (int j = 0; j < 4; ++j) {
    int c = threadIdx.x * 4 + j;
    out[(size_t)row * C + c] = f2b((v[j] - mu) * rstd * g[c] + bta[c]);
  }
}

// ---------------- V transpose: qkv bf16 [4096][3072] -> vT [32][64][2048] ----------------
__global__ void k_vtrans(const short* __restrict__ qkv, short* __restrict__ vT) {
  __shared__ short tile[32][72]; // [t_local][d]
  int b = blockIdx.z, h = blockIdx.y;
  int t0 = blockIdx.x * 32;
  int tx = threadIdx.x; // 0..31
  int ty = threadIdx.y; // 0..7
  const size_t inbase = ((size_t)(b * 2048 + t0)) * 3072 + 2048 + h * 64;
  for (int i = ty; i < 32; i += 8) {
    tile[i][tx]      = qkv[inbase + (size_t)i * 3072 + tx];
    tile[i][tx + 32] = qkv[inbase + (size_t)i * 3072 + tx + 32];
  }
  __syncthreads();
  const size_t outbase = ((size_t)(b * 16 + h) * 64) * 2048 + t0;
  for (int d = ty; d < 64; d += 8)
    vT[outbase + (size_t)d * 2048 + tx] = tile[tx][d];
}

// ---------------- GEMM: out = act(A @ BT^T + bias) (+resid) ----------------
// A: bf16 [M,K] row-major; BT: bf16 [N,K] row-major (i.e. B transposed)
// ACT: 0=none 1=relu 2=gelu. RESID adds fp32 resid[M,N] after act.
template <int BM, int BN, int WGM, int WGN, int ACT, bool RESID, bool OUTF, bool OUTB>
__global__ __launch_bounds__(256, 2) void k_gemm(
    const short* __restrict__ A, const short* __restrict__ BT,
    const float* __restrict__ bias, const float* __restrict__ resid,
    float* __restrict__ outf, short* __restrict__ outb,
    int M, int N, int K) {
  static_assert(WGM * WGN == 4, "4 waves");
  constexpr int TM = BM / WGM, TN = BN / WGN;
  constexpr int FM = TM / 16, FN = TN / 16;
  __shared__ short As[BM * 32];
  __shared__ short Bs[BN * 32];
  const int tid = threadIdx.x;
  const int wid = tid >> 6, l = tid & 63, lr = l & 15, lg = l >> 4;
  const int wm = wid / WGN, wn = wid % WGN;
  const int rowA0 = blockIdx.x * BM;
  const int colB0 = blockIdx.y * BN;

  f32x4 acc[FM][FN];
#pragma unroll
  for (int i = 0; i < FM; ++i)
#pragma unroll
    for (int j = 0; j < FN; ++j) acc[i][j] = f32x4{0.f, 0.f, 0.f, 0.f};

  for (int k0 = 0; k0 < K; k0 += 32) {
    __syncthreads();
#pragma unroll
    for (int it = 0; it < (BM * 64) / 4096; ++it) {
      int bo = it * 4096 + tid * 16;
      int row = bo >> 6, col = (bo & 63) >> 1;
      gload_lds16(A + (size_t)(rowA0 + row) * K + k0 + col, (void*)(As + (bo >> 1)));
    }
#pragma unroll
    for (int it = 0; it < (BN * 64) / 4096; ++it) {
      int bo = it * 4096 + tid * 16;
      int row = bo >> 6, col = (bo & 63) >> 1;
      gload_lds16(BT + (size_t)(colB0 + row) * K + k0 + col, (void*)(Bs + (bo >> 1)));
    }
    __syncthreads();
    bf16x8 af[FM], bfr[FN];
#pragma unroll
    for (int i = 0; i < FM; ++i)
      af[i] = *(const bf16x8*)(As + (wm * TM + i * 16 + lr) * 32 + lg * 8);
#pragma unroll
    for (int j = 0; j < FN; ++j)
      bfr[j] = *(const bf16x8*)(Bs + (wn * TN + j * 16 + lr) * 32 + lg * 8);
#pragma unroll
    for (int i = 0; i < FM; ++i)
#pragma unroll
      for (int j = 0; j < FN; ++j)
        acc[i][j] = mfma16(af[i], bfr[j], acc[i][j]);
  }

  const int row0 = rowA0 + wm * TM + lg * 4;
  const int col0 = colB0 + wn * TN + lr;
#pragma unroll
  for (int i = 0; i < FM; ++i) {
#pragma unroll
    for (int j = 0; j < FN; ++j) {
#pragma unroll
      for (int r = 0; r < 4; ++r) {
        int row = row0 + i * 16 + r;
        int col = col0 + j * 16;
        float v = acc[i][j][r] + bias[col];
        if (ACT == 1) v = fmaxf(v, 0.f);
        if (ACT == 2) v = gelu_f(v);
        size_t idx = (size_t)row * N + col;
        if (RESID) v += resid[idx];
        if (OUTF) outf[idx] = v;
        if (OUTB) outb[idx] = f2b(v);
      }
    }
  }
}

// ---------------- flash-style causal attention ----------------
// qkv bf16 [4096][3072] (q|k|v each 1024 cols, 16 heads x 64)
// vT  bf16 [32][64][2048]; y bf16 [4096][1024]
__global__ __launch_bounds__(256, 2) void k_attn(
    const short* __restrict__ qkv, const short* __restrict__ vT,
    short* __restrict__ y) {
  constexpr int T = 2048, C3 = 3072;
  const int tid = threadIdx.x;
  const int wid = tid >> 6, l = tid & 63, lr = l & 15, lg = l >> 4;
  const int bh = blockIdx.x, b = bh >> 4, h = bh & 15;
  const int q0 = blockIdx.y * 64 + wid * 16; // this wave's 16 q-rows

  __shared__ short Plds[4][16][32]; // per-wave P tile transpose staging

  const short* qptr = qkv + (size_t)(b * T + q0) * C3 + h * 64;
  bf16x8 qf0 = *(const bf16x8*)(qptr + (size_t)lr * C3 + lg * 8);
  bf16x8 qf1 = *(const bf16x8*)(qptr + (size_t)lr * C3 + 32 + lg * 8);

  const short* kbase = qkv + (size_t)(b * T) * C3 + 1024 + h * 64;
  const short* vtb = vT + (size_t)bh * 64 * 2048;

  f32x4 o[4];
#pragma unroll
  for (int d = 0; d < 4; ++d) o[d] = f32x4{0.f, 0.f, 0.f, 0.f};
  float mrow[4] = {-1e30f, -1e30f, -1e30f, -1e30f};
  float lsum[4] = {0.f, 0.f, 0.f, 0.f};

  const int kvend = q0 + 16;
  for (int kv0 = 0; kv0 < kvend; kv0 += 32) {
    bf16x8 kf00 = *(const bf16x8*)(kbase + (size_t)(kv0 + lr) * C3 + lg * 8);
    bf16x8 kf01 = *(const bf16x8*)(kbase + (size_t)(kv0 + lr) * C3 + 32 + lg * 8);
    bf16x8 kf10 = *(const bf16x8*)(kbase + (size_t)(kv0 + 16 + lr) * C3 + lg * 8);
    bf16x8 kf11 = *(const bf16x8*)(kbase + (size_t)(kv0 + 16 + lr) * C3 + 32 + lg * 8);
    f32x4 s0 = {0.f, 0.f, 0.f, 0.f}, s1 = {0.f, 0.f, 0.f, 0.f};
    s0 = mfma16(qf0, kf00, s0);
    s0 = mfma16(qf1, kf01, s0);
    s1 = mfma16(qf0, kf10, s1);
    s1 = mfma16(qf1, kf11, s1);
#pragma unroll
    for (int r = 0; r < 4; ++r) {
      const int qrow = q0 + lg * 4 + r;
      float v0 = s0[r] * 0.125f;
      float v1 = s1[r] * 0.125f;
      if (kv0 + lr > qrow) v0 = -1e30f;
      if (kv0 + 16 + lr > qrow) v1 = -1e30f;
      float mt = fmaxf(v0, v1);
      mt = fmaxf(mt, __shfl_xor(mt, 1));
      mt = fmaxf(mt, __shfl_xor(mt, 2));
      mt = fmaxf(mt, __shfl_xor(mt, 4));
      mt = fmaxf(mt, __shfl_xor(mt, 8));
      float mnew = fmaxf(mrow[r], mt);
      float corr = __expf(mrow[r] - mnew);
      mrow[r] = mnew;
      float p0 = __expf(v0 - mnew);
      float p1 = __expf(v1 - mnew);
      lsum[r] = lsum[r] * corr + p0 + p1;
      o[0][r] *= corr; o[1][r] *= corr; o[2][r] *= corr; o[3][r] *= corr;
      Plds[wid][lg * 4 + r][lr] = f2b(p0);
      Plds[wid][lg * 4 + r][16 + lr] = f2b(p1);
    }
    bf16x8 pf = *(const bf16x8*)(&Plds[wid][lr][lg * 8]);
#pragma unroll
    for (int db = 0; db < 4; ++db) {
      bf16x8 vf = *(const bf16x8*)(vtb + (size_t)(db * 16 + lr) * 2048 + kv0 + lg * 8);
      o[db] = mfma16(pf, vf, o[db]);
    }
  }
  float inv[4];
#pragma unroll
  for (int r = 0; r < 4; ++r) {
    float s = lsum[r];
    s += __shfl_xor(s, 1); s += __shfl_xor(s, 2);
    s += __shfl_xor(s, 4); s += __shfl_xor(s, 8);
    inv[r] = 1.f / s;
  }
#pragma unroll
  for (int db = 0; db < 4; ++db)
#pragma unroll
    for (int r = 0; r < 4; ++r)
      y[(size_t)(b * T + q0 + lg * 4 + r) * 1024 + h * 64 + db * 16 + lr] =
          f2b(o[db][r] * inv[r]);
}

extern "C" void kernel_launch(void* const* d_in, const int* in_sizes, int n_in,
                              void* d_out, int out_size, void* d_ws, size_t ws_size,
                              hipStream_t stream) {
  (void)in_sizes; (void)n_in; (void)out_size; (void)ws_size;
  const float* x0     = (const float*)d_in[0];
  const float* ln1_g  = (const float*)d_in[1];
  const float* ln1_b  = (const float*)d_in[2];
  const float* attn_w = (const float*)d_in[3];
  const float* attn_b = (const float*)d_in[4];
  const float* proj_w = (const float*)d_in[5];
  const float* proj_b = (const float*)d_in[6];
  const float* a1_dw  = (const float*)d_in[7];
  const float* a1_db  = (const float*)d_in[8];
  const float* a1_uw  = (const float*)d_in[9];
  const float* a1_ub  = (const float*)d_in[10];
  const float* ln2_g  = (const float*)d_in[11];
  const float* ln2_b  = (const float*)d_in[12];
  const float* fc_w   = (const float*)d_in[13];
  const float* fc_b   = (const float*)d_in[14];
  const float* mlp_pw = (const float*)d_in[15];
  const float* mlp_pb = (const float*)d_in[16];
  const float* a2_dw  = (const float*)d_in[17];
  const float* a2_db  = (const float*)d_in[18];
  const float* a2_uw  = (const float*)d_in[19];
  const float* a2_ub  = (const float*)d_in[20];

  char* ws = (char*)d_ws;
  size_t off = 0;
  auto alloc = [&](size_t bytes) {
    char* p = ws + off;
    off = (off + bytes + 255) & ~(size_t)255;
    return p;
  };

  short* attn_wT = (short*)alloc(3072ull * 1024 * 2);
  short* proj_wT = (short*)alloc(1024ull * 1024 * 2);
  short* fc_wT   = (short*)alloc(4096ull * 1024 * 2);
  short* mlp_pwT = (short*)alloc(1024ull * 4096 * 2);
  short* a1_dwT  = (short*)alloc(64ull * 1024 * 2);
  short* a1_uwT  = (short*)alloc(1024ull * 64 * 2);
  short* a2_dwT  = (short*)alloc(64ull * 1024 * 2);
  short* a2_uwT  = (short*)alloc(1024ull * 64 * 2);
  short* lnb     = (short*)alloc(4096ull * 1024 * 2);
  char*  big     = alloc(4096ull * 4096 * 2); // qkvb(25.2M)+vT(8.4M) then fcb(33.6M)
  short* qkvb    = (short*)big;
  short* vTb     = (short*)(big + 4096ull * 3072 * 2);
  short* fcb     = (short*)big;
  short* yb      = (short*)alloc(4096ull * 1024 * 2);
  float* x1f     = (float*)alloc(4096ull * 1024 * 4); // reused as x3f
  float* x2f     = (float*)alloc(4096ull * 1024 * 4);
  short* x1b     = (short*)alloc(4096ull * 1024 * 2); // reused as x3b
  short* hb      = (short*)alloc(4096ull * 64 * 2);

  dim3 tb(32, 8);
  k_wt<<<dim3(3072 / 32, 1024 / 32), tb, 0, stream>>>(attn_w, attn_wT, 1024, 3072);
  k_wt<<<dim3(1024 / 32, 1024 / 32), tb, 0, stream>>>(proj_w, proj_wT, 1024, 1024);
  k_wt<<<dim3(4096 / 32, 1024 / 32), tb, 0, stream>>>(fc_w, fc_wT, 1024, 4096);
  k_wt<<<dim3(1024 / 32, 4096 / 32), tb, 0, stream>>>(mlp_pw, mlp_pwT, 4096, 1024);
  k_wt<<<dim3(64 / 32, 1024 / 32), tb, 0, stream>>>(a1_dw, a1_dwT, 1024, 64);
  k_wt<<<dim3(1024 / 32, 64 / 32), tb, 0, stream>>>(a1_uw, a1_uwT, 64, 1024);
  k_wt<<<dim3(64 / 32, 1024 / 32), tb, 0, stream>>>(a2_dw, a2_dwT, 1024, 64);
  k_wt<<<dim3(1024 / 32, 64 / 32), tb, 0, stream>>>(a2_uw, a2_uwT, 64, 1024);

  // x -> ln1 (bf16)
  k_layernorm<<<4096, 256, 0, stream>>>(x0, ln1_g, ln1_b, lnb);

  // qkv = ln1 @ attn_w + attn_b
  k_gemm<128, 128, 2, 2, 0, false, false, true><<<dim3(32, 24), 256, 0, stream>>>(
      lnb, attn_wT, attn_b, nullptr, nullptr, qkvb, 4096, 3072, 1024);

  // v -> vT [bh][d][t]
  k_vtrans<<<dim3(64, 16, 2), tb, 0, stream>>>(qkvb, vTb);

  // y = attention(q,k,v)
  k_attn<<<dim3(32, 32), 256, 0, stream>>>(qkvb, vTb, yb);

  // x1 = x0 + y @ proj_w + proj_b   (fp32 + bf16)
  k_gemm<128, 128, 2, 2, 0, true, true, true><<<dim3(32, 8), 256, 0, stream>>>(
      yb, proj_wT, proj_b, x0, x1f, x1b, 4096, 1024, 1024);

  // h = relu(x1 @ a1_dw + a1_db)
  k_gemm<128, 64, 4, 1, 1, false, false, true><<<dim3(32, 1), 256, 0, stream>>>(
      x1b, a1_dwT, a1_db, nullptr, nullptr, hb, 4096, 64, 1024);

  // x2 = x1 + h @ a1_uw + a1_ub  (fp32 only)
  k_gemm<128, 128, 2, 2, 0, true, true, false><<<dim3(32, 8), 256, 0, stream>>>(
      hb, a1_uwT, a1_ub, x1f, x2f, nullptr, 4096, 1024, 64);

  // ln2(x2) (bf16)
  k_layernorm<<<4096, 256, 0, stream>>>(x2f, ln2_g, ln2_b, lnb);

  // fcb = gelu(ln2 @ fc_w + fc_b)
  k_gemm<128, 128, 2, 2, 2, false, false, true><<<dim3(32, 32), 256, 0, stream>>>(
      lnb, fc_wT, fc_b, nullptr, nullptr, fcb, 4096, 4096, 1024);

  // x3 = x2 + fcb @ mlp_pw + mlp_pb  (fp32 + bf16) -> reuse x1f/x1b
  k_gemm<128, 128, 2, 2, 0, true, true, true><<<dim3(32, 8), 256, 0, stream>>>(
      fcb, mlp_pwT, mlp_pb, x2f, x1f, x1b, 4096, 1024, 4096);

  // h = relu(x3 @ a2_dw + a2_db)
  k_gemm<128, 64, 4, 1, 1, false, false, true><<<dim3(32, 1), 256, 0, stream>>>(
      x1b, a2_dwT, a2_db, nullptr, nullptr, hb, 4096, 64, 1024);

  // out = x3 + h @ a2_uw + a2_ub  (fp32 -> d_out)
  k_gemm<128, 128, 2, 2, 0, true, true, false><<<dim3(32, 8), 256, 0, stream>>>(
      hb, a2_uwT, a2_ub, x1f, (float*)d_out, nullptr, 4096, 1024, 64);
}